// Round 1
// baseline (20744.536 us; speedup 1.0000x reference)
//
#include <hip/hip_runtime.h>
#include <cmath>

#define SEQ   512
#define BATCH 64
#define DIN   1024
#define DH    1024

// ---------------------------------------------------------------------------
// Phase 1: x_proj[m][n] = sum_k X[m][k] * W_ih[n][k] + (b_ih[n] + b_hh[n])
// M = SEQ*BATCH = 32768, N = DH = 1024, K = DIN = 1024.
// Written straight into d_out[s][b][h] (same flat layout, m = s*BATCH+b).
// Simple fp32 64x64 tile, 4x4 per thread, +1 LDS pad. Correctness-first.
// ---------------------------------------------------------------------------
__global__ __launch_bounds__(256) void proj_kernel(
    const float* __restrict__ X, const float* __restrict__ W,
    const float* __restrict__ b_ih, const float* __restrict__ b_hh,
    float* __restrict__ C) {
  __shared__ float As[64][17];
  __shared__ float Bs[64][17];
  const int m0 = blockIdx.x * 64;   // 512 blocks
  const int n0 = blockIdx.y * 64;   // 16 blocks
  const int tid = threadIdx.x;
  const int tm = tid >> 4;          // 0..15
  const int tn = tid & 15;          // 0..15
  const int lrow = tid >> 2;        // 0..63 (staging row)
  const int lk4  = (tid & 3) * 4;   // 0,4,8,12 (staging k offset)

  float acc[4][4];
#pragma unroll
  for (int i = 0; i < 4; ++i)
#pragma unroll
    for (int j = 0; j < 4; ++j) acc[i][j] = 0.f;

  for (int kt = 0; kt < DIN; kt += 16) {
    float4 av = *(const float4*)(X + (size_t)(m0 + lrow) * DIN + kt + lk4);
    float4 bv = *(const float4*)(W + (size_t)(n0 + lrow) * DIN + kt + lk4);
    __syncthreads();
    As[lrow][lk4 + 0] = av.x; As[lrow][lk4 + 1] = av.y;
    As[lrow][lk4 + 2] = av.z; As[lrow][lk4 + 3] = av.w;
    Bs[lrow][lk4 + 0] = bv.x; Bs[lrow][lk4 + 1] = bv.y;
    Bs[lrow][lk4 + 2] = bv.z; Bs[lrow][lk4 + 3] = bv.w;
    __syncthreads();
#pragma unroll
    for (int kk = 0; kk < 16; ++kk) {
      float a[4], b[4];
#pragma unroll
      for (int i = 0; i < 4; ++i) a[i] = As[tm * 4 + i][kk];
#pragma unroll
      for (int j = 0; j < 4; ++j) b[j] = Bs[tn * 4 + j][kk];
#pragma unroll
      for (int i = 0; i < 4; ++i)
#pragma unroll
        for (int j = 0; j < 4; ++j) acc[i][j] += a[i] * b[j];
    }
  }

#pragma unroll
  for (int j = 0; j < 4; ++j) {
    const int n = n0 + tn * 4 + j;
    const float bias = b_ih[n] + b_hh[n];
#pragma unroll
    for (int i = 0; i < 4; ++i) {
      const int m = m0 + tm * 4 + i;
      C[(size_t)m * DH + n] = acc[i][j] + bias;
    }
  }
}

// ---------------------------------------------------------------------------
// Phase 2 (one launch per time step, baseline):
// h_t[b][j] = tanh(xp[t][b][j] + sum_k W_hh[j][k] * h_{t-1}[b][k])
// Wave layout: 64 lanes = 64 batches (same j) -> W_hh row reads are
// wave-uniform broadcasts; h reads are strided but tiny working set (L1-hot).
// out[t] holds xp on entry, h_t on exit. t==SEQ-1 also writes h_last.
// ---------------------------------------------------------------------------
__global__ __launch_bounds__(256) void rnn_step(
    const float* __restrict__ h_prev, const float* __restrict__ W_hh,
    float* __restrict__ out, int t) {
  const int j = blockIdx.x * 4 + (threadIdx.x >> 6);  // 0..1023
  const int b = threadIdx.x & 63;                     // 0..63
  const float4* wr = (const float4*)(W_hh + (size_t)j * DH);
  const float4* hr = (const float4*)(h_prev + (size_t)b * DH);
  float acc = 0.f;
#pragma unroll 4
  for (int k = 0; k < DH / 4; ++k) {
    float4 w = wr[k];
    float4 h = hr[k];
    acc += w.x * h.x + w.y * h.y + w.z * h.z + w.w * h.w;
  }
  const size_t oi = ((size_t)t * BATCH + b) * DH + j;
  const float v = tanhf(out[oi] + acc);
  out[oi] = v;
  if (t == SEQ - 1) {
    out[(size_t)SEQ * BATCH * DH + (size_t)b * DH + j] = v;
  }
}

extern "C" void kernel_launch(void* const* d_in, const int* in_sizes, int n_in,
                              void* d_out, int out_size, void* d_ws,
                              size_t ws_size, hipStream_t stream) {
  const float* x    = (const float*)d_in[0];
  const float* h0   = (const float*)d_in[1];
  const float* W_ih = (const float*)d_in[2];
  const float* b_ih = (const float*)d_in[3];
  const float* W_hh = (const float*)d_in[4];
  const float* b_hh = (const float*)d_in[5];
  float* out = (float*)d_out;

  // Phase 1: input projection + both biases -> d_out[s][b][h]
  hipLaunchKernelGGL(proj_kernel, dim3(512, 16), dim3(256), 0, stream,
                     x, W_ih, b_ih, b_hh, out);

  // Phase 2: sequential scan, one launch per step (baseline)
  for (int t = 0; t < SEQ; ++t) {
    const float* hp = (t == 0) ? h0 : out + (size_t)(t - 1) * BATCH * DH;
    hipLaunchKernelGGL(rnn_step, dim3(256), dim3(256), 0, stream,
                       hp, W_hh, out, t);
  }
}